// Round 5
// baseline (93.721 us; speedup 1.0000x reference)
//
#include <hip/hip_runtime.h>
#include <hip/hip_bf16.h>
#include <stdint.h>

typedef unsigned short u16;
typedef unsigned int u32;
typedef __attribute__((ext_vector_type(8))) short short8;
typedef __attribute__((ext_vector_type(4))) short short4_t;
typedef __attribute__((ext_vector_type(4))) float f32x4;

#define MFMA16(A,B,C) __builtin_amdgcn_mfma_f32_16x16x32_bf16((A),(B),(C),0,0,0)
#define L2E 1.4426950408889634f

__device__ __forceinline__ u16 f2bf(float f) {
  u32 x = __float_as_uint(f);
  u32 r = x + 0x7fffu + ((x >> 16) & 1u);   // RNE, finite inputs only
  return (u16)(r >> 16);
}
__device__ __forceinline__ float bf2f(short v) {
  return __uint_as_float((u32)(u16)v << 16);
}
// two f32 -> packed bf16x2 (lo=a, hi=b) via the documented HIP API (RNE).
__device__ __forceinline__ u32 pack_bf2(float a, float b) {
  __hip_bfloat162 h = __float22bfloat162_rn(make_float2(a, b));
  u32 u; __builtin_memcpy(&u, &h, 4); return u;
}
__device__ __forceinline__ short8 mk_frag(u32 w0, u32 w1, u32 w2, u32 w3) {
  union { u32 u[4]; short8 s; } cv;
  cv.u[0] = w0; cv.u[1] = w1; cv.u[2] = w2; cv.u[3] = w3;
  return cv.s;
}

// ---------------- kernel 0: transpose+cast the 6 flag-selected matrices ----
// matT[m][n][k] = M[k][n] as bf16.  m: 0=q 1=k1 2=v1 3=k2 4=v2 5=W_final
__global__ void kprep(const float* R_q, const float* R_k, const float* R_v,
                      const float* R_W, const float* F_q, const float* F_k,
                      const float* F_v, const float* F_W, const int* flagp,
                      u16* matT)
{
  int flag = *flagp;
  const float* S;
  int m = blockIdx.x;
  if (flag) {
    const float* s[6] = {R_q, R_k, R_v, F_k, F_v, R_W}; S = s[m];
  } else {
    const float* s[6] = {F_q, F_k, F_v, R_k, R_v, F_W}; S = s[m];
  }
  u16* dst = matT + m * 16384;
  int base = blockIdx.y * 2048;
  for (int idx = base + threadIdx.x; idx < base + 2048; idx += blockDim.x) {
    int k = idx >> 7, n = idx & 127;
    dst[n * 128 + k] = f2bf(S[idx]);
  }
}

// ---------------- kernel 1: 5 projections, packed layouts -----------------
// g=0: qT (b,32,L)   g=1: L2E*k1 -> KQ[:, 0:32]   g=3: L2E*alpha*k2 -> KQ[:,32:64]
// g=2: v1 -> Vc[:,0:32]                           g=4: v2 -> Vc[:,32:64]
// alpha (affinity softmax) computed in-kernel for g==3 blocks.
__global__ __launch_bounds__(256) void kproj(const float* __restrict__ head,
    const float* __restrict__ tail, const u16* __restrict__ matT,
    const float* __restrict__ conv_w, const float* __restrict__ conv_b,
    const float* __restrict__ bn_w, const float* __restrict__ bn_b,
    const float* __restrict__ bn_mean, const float* __restrict__ bn_var,
    u16* __restrict__ qT, u16* __restrict__ KQ,
    u16* __restrict__ Vc, const int* __restrict__ flagp)
{
  __shared__ u16 lds_t[128][34];         // [w][c] transposed tile, padded
  __shared__ float s_alpha[128];
  const int flag = *flagp;
  const float* X1 = flag ? head : tail;
  const float* X2 = flag ? tail : head;
  const int bh = blockIdx.x, g = blockIdx.y;
  const int b = bh >> 5, h = bh & 31;
  const float* src = (g < 3) ? X1 : X2;
  const u16* Bm = matT + g * 16384;
  const int tid = threadIdx.x, lane = tid & 63, wid = tid >> 6;
  const int lrow = lane & 15, lg = lane >> 4;
  const int rt = wid & 1, cbase = (wid >> 1) * 64;

  if (g == 3) {                           // fused affinity alpha for this (b,h)
    if (tid < 128) {
      int w = tid;
      const float* hp = head + ((size_t)b * 1024 + h) * 128 + w;
      const float* tp = tail + ((size_t)b * 1024 + h) * 128 + w;
      float a0 = 0.f, a1 = 0.f;
      for (int c = 0; c < 32; ++c) {
        float xh = hp[c * 4096];
        float xt = tp[c * 4096];
        a0 += xh * conv_w[c]      + xt * conv_w[32 + c];
        a1 += xh * conv_w[64 + c] + xt * conv_w[96 + c];
      }
      const float eps = 1e-5f;
      a0 += conv_b[0]; a1 += conv_b[1];
      a0 = (a0 - bn_mean[0]) * (bn_w[0] * rsqrtf(bn_var[0] + eps)) + bn_b[0];
      a1 = (a1 - bn_mean[1]) * (bn_w[1] * rsqrtf(bn_var[1] + eps)) + bn_b[1];
      a0 = fmaxf(a0, 0.f); a1 = fmaxf(a1, 0.f);
      float asel = flag ? a0 : a1, aoth = flag ? a1 : a0;
      s_alpha[w] = 1.f / (1.f + __expf(aoth - asel));
    }
    __syncthreads();
  }

  f32x4 acc[4] = {};
  const float* Arow = src + (((size_t)b * 32 + rt * 16 + lrow) * 32 + h) * 128;
  #pragma unroll
  for (int k0 = 0; k0 < 128; k0 += 32) {
    short8 af;
    const float* ap = Arow + k0 + lg * 8;
    #pragma unroll
    for (int j = 0; j < 8; ++j) af[j] = (short)f2bf(ap[j]);
    #pragma unroll
    for (int cc = 0; cc < 4; ++cc) {
      short8 bf = *reinterpret_cast<const short8*>(
          Bm + (cbase + cc * 16 + lrow) * 128 + k0 + lg * 8);
      acc[cc] = MFMA16(af, bf, acc[cc]);
    }
  }
  #pragma unroll
  for (int cc = 0; cc < 4; ++cc) {
    int n = cbase + cc * 16 + lrow;                 // w
    float asc = (g == 1) ? L2E : 1.f;
    if (g == 3) asc = s_alpha[n] * L2E;
    #pragma unroll
    for (int rr = 0; rr < 4; ++rr) {
      int c = rt * 16 + lg * 4 + rr;
      lds_t[n][c] = f2bf(acc[cc][rr] * asc);
    }
  }
  __syncthreads();
  if (g == 0) {
    int c = tid >> 3, w0 = (tid & 7) * 16;
    int tw[8];
    #pragma unroll
    for (int i2 = 0; i2 < 8; ++i2)
      tw[i2] = (int)lds_t[w0 + 2 * i2][c] | ((int)lds_t[w0 + 2 * i2 + 1][c] << 16);
    int4* dst = reinterpret_cast<int4*>(qT + ((size_t)b * 32 + c) * 4096 + h * 128 + w0);
    dst[0] = make_int4(tw[0], tw[1], tw[2], tw[3]);
    dst[1] = make_int4(tw[4], tw[5], tw[6], tw[7]);
  } else if (tid < 128) {
    int w = tid;
    int tw[16];
    #pragma unroll
    for (int i2 = 0; i2 < 16; ++i2)
      tw[i2] = (int)lds_t[w][2 * i2] | ((int)lds_t[w][2 * i2 + 1] << 16);
    u16* base = (g == 2 || g == 4) ? Vc : KQ;
    int coff = (g >= 3) ? 32 : 0;
    int4* dst = reinterpret_cast<int4*>(base + ((size_t)b * 4096 + h * 128 + w) * 64 + coff);
    dst[0] = make_int4(tw[0],  tw[1],  tw[2],  tw[3]);
    dst[1] = make_int4(tw[4],  tw[5],  tw[6],  tw[7]);
    dst[2] = make_int4(tw[8],  tw[9],  tw[10], tw[11]);
    dst[3] = make_int4(tw[12], tw[13], tw[14], tw[15]);
  }
}

// ---------------- kernel 2: flash attention, j-split partials -------------
// Swapped QK^T: S^T-tile = mfma(A = V rows (j as M), B = KQ rows (i as N)).
// V rows are PERMUTED at staging: LDS row r holds global row j0 + pj(r),
//   pj(r) = (r&32) + ((r>>2)&3)*8 + ((r>>4)&1)*4 + (r&3)
// so lane (lrow,lg) ends up holding P[i][j = w*32 + lg*8 + 0..7] across the
// sub-pair of each 32-j window -> score fragments ARE the PV K=32 B-operand
// (kk order: st[2w][0..3], st[2w+1][0..3]). Zero cross-lane ops in PV.
// Softmax is j-permutation-invariant. qT (A-operand) keeps natural layout.
// Each block covers j in [sp*512, sp*512+512); emits unnormalized partial
// (m, l, O) for its 64 i-rows.  pO layout: [b][sp][c][i] (i fastest).
__global__ __launch_bounds__(256, 8) void kattn(const u16* __restrict__ qT,
    const u16* __restrict__ KQ, const u16* __restrict__ Vc,
    u16* __restrict__ pO, float* __restrict__ pm, float* __restrict__ pl)
{
  __shared__ __align__(16) char lds_v[2][8192];
  const int b = blockIdx.y;
  const int i0 = blockIdx.x * 64;
  const int sp = blockIdx.z;
  const int jbase = sp * 512;
  const int tid = threadIdx.x, lane = tid & 63, wid = tid >> 6;
  const int lrow = lane & 15, lg = lane >> 4;

  const u16* KQb = KQ + (size_t)b * 4096 * 64;
  const u16* Vb  = Vc + (size_t)b * 4096 * 64;
  const u16* qTb = qT + (size_t)b * 32 * 4096;

  // B-frags for this wave's 16 i-rows, direct from global (L2-resident)
  short8 bkq[2];
  {
    int r = i0 + wid * 16 + lrow;
    #pragma unroll
    for (int kc = 0; kc < 2; ++kc)
      bkq[kc] = *reinterpret_cast<const short8*>(KQb + (size_t)r * 64 + kc * 32 + lg * 8);
  }

  // staging geometry: this thread owns LDS rows sr, sr+32; source rows permuted
  const int sr = tid >> 3, sx = (tid & 7) * 16;
  const int pr = (((sr >> 2) & 3) << 3) + (((sr >> 4) & 1) << 2) + (sr & 3);

  // stage V tile 0 (permuted source rows), XOR-swizzled 128B LDS rows
  #pragma unroll
  for (int q = 0; q < 2; ++q) {
    int r = sr + q * 32, gr = pr + q * 32;
    int4 v = *reinterpret_cast<const int4*>(
        reinterpret_cast<const char*>(Vb + (size_t)(jbase + gr) * 64) + sx);
    *reinterpret_cast<int4*>(lds_v[0] + r * 128 + (sx ^ ((r & 7) << 4))) = v;
  }
  __syncthreads();

  float m_run = -1e30f, l_run = 0.f;
  f32x4 accO[2] = {};
  int4 stg[2];

  for (int t = 0; t < 8; ++t) {
    const int buf = t & 1;
    if (t < 7) {                        // T14: issue next-tile loads early
      const u16* Vn = Vb + (size_t)(jbase + (t + 1) * 64) * 64;
      #pragma unroll
      for (int q = 0; q < 2; ++q) {
        int gr = pr + q * 32;
        stg[q] = *reinterpret_cast<const int4*>(
            reinterpret_cast<const char*>(Vn + (size_t)gr * 64) + sx);
      }
    }
    const int j0 = jbase + t * 64;
    // hoist PV A-frags (qT rows, L2-resident): latency overlaps QK+softmax
    short8 aq[2][2];
    #pragma unroll
    for (int w = 0; w < 2; ++w)
      #pragma unroll
      for (int ct = 0; ct < 2; ++ct)
        aq[w][ct] = *reinterpret_cast<const short8*>(
            qTb + (size_t)(ct * 16 + lrow) * 4096 + j0 + w * 32 + lg * 8);
    // scores: 4 j-subtiles, K=64 in 2 chunks
    f32x4 st[4];
    __builtin_amdgcn_s_setprio(1);
    #pragma unroll
    for (int sub = 0; sub < 4; ++sub) {
      f32x4 a = {};
      #pragma unroll
      for (int kc = 0; kc < 2; ++kc) {
        int r = sub * 16 + lrow;
        int xs = kc * 64 + lg * 16;
        short8 av = *reinterpret_cast<const short8*>(
            lds_v[buf] + r * 128 + (xs ^ ((r & 7) << 4)));
        a = MFMA16(av, bkq[kc], a);
      }
      st[sub] = a;
    }
    __builtin_amdgcn_s_setprio(0);
    // online softmax (row i lane-local; reduce over lanes lrow,+16,+32,+48)
    float tm = -1e30f;
    #pragma unroll
    for (int sub = 0; sub < 4; ++sub)
      #pragma unroll
      for (int rr = 0; rr < 4; ++rr) tm = fmaxf(tm, st[sub][rr]);
    tm = fmaxf(tm, __shfl_xor(tm, 16, 64));
    tm = fmaxf(tm, __shfl_xor(tm, 32, 64));
    // defer-max (T13): skip rescale while tile max stays within 2^8 of m_run
    if (!__all((int)(tm <= m_run + 8.f))) {
      float m_new = fmaxf(m_run, tm);
      float scale = exp2f(m_run - m_new);
      l_run *= scale;
      #pragma unroll
      for (int ct = 0; ct < 2; ++ct)
        #pragma unroll
        for (int rr = 0; rr < 4; ++rr) accO[ct][rr] *= scale;
      m_run = m_new;
    }
    float ps = 0.f;
    #pragma unroll
    for (int sub = 0; sub < 4; ++sub)
      #pragma unroll
      for (int rr = 0; rr < 4; ++rr) {
        float p = exp2f(st[sub][rr] - m_run);
        st[sub][rr] = p;
        ps += p;
      }
    ps += __shfl_xor(ps, 16, 64);
    ps += __shfl_xor(ps, 32, 64);
    l_run += ps;

    // PV: O^T += mfma(A = qT rows, B = P^T). B-frag is the packed scores
    // directly (V-row permutation made the lane->j map match the B layout).
    __builtin_amdgcn_s_setprio(1);
    #pragma unroll
    for (int w = 0; w < 2; ++w) {
      short8 bp = mk_frag(pack_bf2(st[2 * w][0],     st[2 * w][1]),
                          pack_bf2(st[2 * w][2],     st[2 * w][3]),
                          pack_bf2(st[2 * w + 1][0], st[2 * w + 1][1]),
                          pack_bf2(st[2 * w + 1][2], st[2 * w + 1][3]));
      #pragma unroll
      for (int ct = 0; ct < 2; ++ct)
        accO[ct] = MFMA16(aq[w][ct], bp, accO[ct]);
    }
    __builtin_amdgcn_s_setprio(0);

    if (t < 7) {
      #pragma unroll
      for (int q = 0; q < 2; ++q) {
        int r = sr + q * 32;
        *reinterpret_cast<int4*>(lds_v[buf ^ 1] + r * 128 + (sx ^ ((r & 7) << 4))) = stg[q];
      }
      __syncthreads();
    }
  }

  // write unnormalized partials; pO transposed [b][sp][c][i]
  const int i = i0 + wid * 16 + lrow;
  u16* pOb = pO + (size_t)((b * 8 + sp) * 32) * 4096;
  #pragma unroll
  for (int ct = 0; ct < 2; ++ct)
    #pragma unroll
    for (int rr = 0; rr < 4; ++rr)
      pOb[(size_t)(ct * 16 + lg * 4 + rr) * 4096 + i] = f2bf(accO[ct][rr]);
  if (lg == 0) {
    pm[(b * 8 + sp) * 4096 + i] = m_run;
    pl[(b * 8 + sp) * 4096 + i] = l_run;
  }
}

// ---------------- kernel 3: merge partials + final mix + residual ---------
// Block = 16 output rows (one b, one c, h in [h0,h0+16)).  Phase 1 reduces
// the 8 j-split partials for this c across the block's 2048 i-values into a
// 16x128 bf16 y-tile in LDS; phase 2 is the 128x128 GEMM + residual.
__global__ __launch_bounds__(128) void kout(const u16* __restrict__ pO,
    const float* __restrict__ pm, const float* __restrict__ pl,
    const u16* __restrict__ matT, const float* __restrict__ head,
    const float* __restrict__ tail, const int* __restrict__ flagp,
    float* __restrict__ out)
{
  __shared__ u16 ylds[16][136];          // padded rows (272 B) vs bank conflicts
  const int flag = *flagp;
  const float* X1 = flag ? head : tail;
  const u16* Bm = matT + 5 * 16384;
  const int tid = threadIdx.x;
  const int rbase = blockIdx.x * 16;
  const int b = rbase >> 10, c = (rbase >> 5) & 31, h0 = rbase & 31;
  const int ioff = h0 * 128 + tid * 16;  // this thread's 16 i-values

  // ---- phase 1: reduction over the 8 splits, 4 i at a time ----
  #pragma unroll
  for (int iq = 0; iq < 4; ++iq) {
    float4 msp[8];
    #pragma unroll
    for (int sp = 0; sp < 8; ++sp)
      msp[sp] = *reinterpret_cast<const float4*>(
          pm + (size_t)((b * 8 + sp) * 4096) + ioff + iq * 4);
    float4 M4 = msp[0];
    #pragma unroll
    for (int sp = 1; sp < 8; ++sp) {
      M4.x = fmaxf(M4.x, msp[sp].x); M4.y = fmaxf(M4.y, msp[sp].y);
      M4.z = fmaxf(M4.z, msp[sp].z); M4.w = fmaxf(M4.w, msp[sp].w);
    }
    float4 L4 = {0.f, 0.f, 0.f, 0.f}, y4 = {0.f, 0.f, 0.f, 0.f};
    #pragma unroll
    for (int sp = 0; sp < 8; ++sp) {
      float4 w4;
      w4.x = exp2f(msp[sp].x - M4.x); w4.y = exp2f(msp[sp].y - M4.y);
      w4.z = exp2f(msp[sp].z - M4.z); w4.w = exp2f(msp[sp].w - M4.w);
      float4 l4 = *reinterpret_cast<const float4*>(
          pl + (size_t)((b * 8 + sp) * 4096) + ioff + iq * 4);
      L4.x += w4.x * l4.x; L4.y += w4.y * l4.y;
      L4.z += w4.z * l4.z; L4.w += w4.w * l4.w;
      short4_t o4 = *reinterpret_cast<const short4_t*>(
          pO + (size_t)(((b * 8 + sp) * 32 + c)) * 4096 + ioff + iq * 4);
      y4.x += w4.x * bf2f(o4[0]); y4.y += w4.y * bf2f(o4[1]);
      y4.z += w4.z * bf2f(o4[2]); y4.w += w4.w * bf2f(o4[3]);
    }
    y4.x /= L4.x; y4.y /= L4.y; y4.z /= L4.z; y4.w /= L4.w;
    uint2 pk2;
    pk2.x = pack_bf2(y4.x, y4.y);
    pk2.y = pack_bf2(y4.z, y4.w);
    *reinterpret_cast<uint2*>(&ylds[tid >> 3][(tid & 7) * 16 + iq * 4]) = pk2;
  }
  __syncthreads();

  // ---- phase 2: out[rbase..rbase+16][:] = ylds @ W + X1 ----
  const int lane = tid & 63, wid = tid >> 6;
  const int lrow = lane & 15, lg = lane >> 4;
  const int ctbase = wid * 4;
  f32x4 acc[4] = {};
  #pragma unroll
  for (int k0 = 0; k0 < 128; k0 += 32) {
    short8 af = *reinterpret_cast<const short8*>(&ylds[lrow][k0 + lg * 8]);
    #pragma unroll
    for (int cc = 0; cc < 4; ++cc) {
      short8 bf = *reinterpret_cast<const short8*>(
          Bm + (size_t)((ctbase + cc) * 16 + lrow) * 128 + k0 + lg * 8);
      acc[cc] = MFMA16(af, bf, acc[cc]);
    }
  }
  #pragma unroll
  for (int cc = 0; cc < 4; ++cc)
    #pragma unroll
    for (int rr = 0; rr < 4; ++rr) {
      int row = rbase + lg * 4 + rr;
      int col = (ctbase + cc) * 16 + lrow;
      size_t idx = (size_t)row * 128 + col;
      out[idx] = acc[cc][rr] + X1[idx];
    }
}

// ---------------- launch ---------------------------------------------------
extern "C" void kernel_launch(void* const* d_in, const int* in_sizes, int n_in,
                              void* d_out, int out_size, void* d_ws, size_t ws_size,
                              hipStream_t stream)
{
  const float* head    = (const float*)d_in[0];
  const float* tail    = (const float*)d_in[1];
  const float* R_q     = (const float*)d_in[2];
  const float* R_k     = (const float*)d_in[3];
  const float* R_v     = (const float*)d_in[4];
  const float* R_W     = (const float*)d_in[5];
  const float* F_q     = (const float*)d_in[6];
  const float* F_k     = (const float*)d_in[7];
  const float* F_v     = (const float*)d_in[8];
  const float* F_W     = (const float*)d_in[9];
  const float* conv_w  = (const float*)d_in[10];
  const float* conv_b  = (const float*)d_in[11];
  const float* bn_w    = (const float*)d_in[12];
  const float* bn_b    = (const float*)d_in[13];
  const float* bn_mean = (const float*)d_in[14];
  const float* bn_var  = (const float*)d_in[15];
  const int*   flagp   = (const int*)d_in[16];
  float* out = (float*)d_out;

  char* ws = (char*)d_ws;
  u16*   matT = (u16*)(ws);               // 196608 B
  u16*   qT   = (u16*)(ws + 262144);      // 1 MB   (b,32,L) bf16
  u16*   KQ   = (u16*)(ws + 1310720);     // 2 MB   (b,L,64) bf16, pre-scaled log2e
  u16*   Vc   = (u16*)(ws + 3407872);     // 2 MB   (b,L,64) bf16
  u16*   pO   = (u16*)(ws + 6553600);     // 8 MB   [b][8][32][L] bf16 partial O
  float* pm   = (float*)(ws + 14942208);  // 512 KB [b][8][L] partial max
  float* pl   = (float*)(ws + 15466496);  // 512 KB [b][8][L] partial sum

  kprep <<<dim3(6, 8), 256, 0, stream>>>(R_q, R_k, R_v, R_W, F_q, F_k, F_v, F_W, flagp, matT);
  kproj <<<dim3(128, 5), 256, 0, stream>>>(head, tail, matT, conv_w, conv_b,
                                           bn_w, bn_b, bn_mean, bn_var,
                                           qT, KQ, Vc, flagp);
  kattn <<<dim3(64, 4, 8), 256, 0, stream>>>(qT, KQ, Vc, pO, pm, pl);
  kout  <<<256, 128, 0, stream>>>(pO, pm, pl, matT, head, tail, flagp, out);
}

// Round 6
// 63.082 us; speedup vs baseline: 1.4857x; 1.4857x over previous
//
#include <hip/hip_runtime.h>
#include <hip/hip_bf16.h>
#include <stdint.h>

typedef unsigned short u16;
typedef unsigned int u32;
typedef __attribute__((ext_vector_type(8))) short short8;
typedef __attribute__((ext_vector_type(4))) short short4_t;
typedef __attribute__((ext_vector_type(4))) float f32x4;

#define MFMA16(A,B,C) __builtin_amdgcn_mfma_f32_16x16x32_bf16((A),(B),(C),0,0,0)
#define L2E 1.4426950408889634f

__device__ __forceinline__ u16 f2bf(float f) {
  u32 x = __float_as_uint(f);
  u32 r = x + 0x7fffu + ((x >> 16) & 1u);   // RNE, finite inputs only
  return (u16)(r >> 16);
}
__device__ __forceinline__ float bf2f(short v) {
  return __uint_as_float((u32)(u16)v << 16);
}
// two f32 -> packed bf16x2 (lo=a, hi=b) via the documented HIP API (RNE).
__device__ __forceinline__ u32 pack_bf2(float a, float b) {
  __hip_bfloat162 h = __float22bfloat162_rn(make_float2(a, b));
  u32 u; __builtin_memcpy(&u, &h, 4); return u;
}
__device__ __forceinline__ short8 mk_frag(u32 w0, u32 w1, u32 w2, u32 w3) {
  union { u32 u[4]; short8 s; } cv;
  cv.u[0] = w0; cv.u[1] = w1; cv.u[2] = w2; cv.u[3] = w3;
  return cv.s;
}

// ---------------- kernel 0: transpose+cast the 6 flag-selected matrices ----
// matT[m][n][k] = M[k][n] as bf16.  m: 0=q 1=k1 2=v1 3=k2 4=v2 5=W_final
__global__ void kprep(const float* R_q, const float* R_k, const float* R_v,
                      const float* R_W, const float* F_q, const float* F_k,
                      const float* F_v, const float* F_W, const int* flagp,
                      u16* matT)
{
  int flag = *flagp;
  const float* S;
  int m = blockIdx.x;
  if (flag) {
    const float* s[6] = {R_q, R_k, R_v, F_k, F_v, R_W}; S = s[m];
  } else {
    const float* s[6] = {F_q, F_k, F_v, R_k, R_v, F_W}; S = s[m];
  }
  u16* dst = matT + m * 16384;
  int base = blockIdx.y * 2048;
  for (int idx = base + threadIdx.x; idx < base + 2048; idx += blockDim.x) {
    int k = idx >> 7, n = idx & 127;
    dst[n * 128 + k] = f2bf(S[idx]);
  }
}

// ---------------- kernel 1: 5 projections, packed layouts -----------------
// g=0: qT (b,32,L)   g=1: L2E*k1 -> KQ[:, 0:32]   g=3: L2E*alpha*k2 -> KQ[:,32:64]
// g=2: v1 -> Vc[:,0:32]                           g=4: v2 -> Vc[:,32:64]
// alpha (affinity softmax) computed in-kernel for g==3 blocks.
__global__ __launch_bounds__(256) void kproj(const float* __restrict__ head,
    const float* __restrict__ tail, const u16* __restrict__ matT,
    const float* __restrict__ conv_w, const float* __restrict__ conv_b,
    const float* __restrict__ bn_w, const float* __restrict__ bn_b,
    const float* __restrict__ bn_mean, const float* __restrict__ bn_var,
    u16* __restrict__ qT, u16* __restrict__ KQ,
    u16* __restrict__ Vc, const int* __restrict__ flagp)
{
  __shared__ u16 lds_t[128][34];         // [w][c] transposed tile, padded
  __shared__ float s_alpha[128];
  const int flag = *flagp;
  const float* X1 = flag ? head : tail;
  const float* X2 = flag ? tail : head;
  const int bh = blockIdx.x, g = blockIdx.y;
  const int b = bh >> 5, h = bh & 31;
  const float* src = (g < 3) ? X1 : X2;
  const u16* Bm = matT + g * 16384;
  const int tid = threadIdx.x, lane = tid & 63, wid = tid >> 6;
  const int lrow = lane & 15, lg = lane >> 4;
  const int rt = wid & 1, cbase = (wid >> 1) * 64;

  if (g == 3) {                           // fused affinity alpha for this (b,h)
    if (tid < 128) {
      int w = tid;
      const float* hp = head + ((size_t)b * 1024 + h) * 128 + w;
      const float* tp = tail + ((size_t)b * 1024 + h) * 128 + w;
      float a0 = 0.f, a1 = 0.f;
      for (int c = 0; c < 32; ++c) {
        float xh = hp[c * 4096];
        float xt = tp[c * 4096];
        a0 += xh * conv_w[c]      + xt * conv_w[32 + c];
        a1 += xh * conv_w[64 + c] + xt * conv_w[96 + c];
      }
      const float eps = 1e-5f;
      a0 += conv_b[0]; a1 += conv_b[1];
      a0 = (a0 - bn_mean[0]) * (bn_w[0] * rsqrtf(bn_var[0] + eps)) + bn_b[0];
      a1 = (a1 - bn_mean[1]) * (bn_w[1] * rsqrtf(bn_var[1] + eps)) + bn_b[1];
      a0 = fmaxf(a0, 0.f); a1 = fmaxf(a1, 0.f);
      float asel = flag ? a0 : a1, aoth = flag ? a1 : a0;
      s_alpha[w] = 1.f / (1.f + __expf(aoth - asel));
    }
    __syncthreads();
  }

  f32x4 acc[4] = {};
  const float* Arow = src + (((size_t)b * 32 + rt * 16 + lrow) * 32 + h) * 128;
  #pragma unroll
  for (int k0 = 0; k0 < 128; k0 += 32) {
    short8 af;
    const float* ap = Arow + k0 + lg * 8;
    #pragma unroll
    for (int j = 0; j < 8; ++j) af[j] = (short)f2bf(ap[j]);
    #pragma unroll
    for (int cc = 0; cc < 4; ++cc) {
      short8 bf = *reinterpret_cast<const short8*>(
          Bm + (cbase + cc * 16 + lrow) * 128 + k0 + lg * 8);
      acc[cc] = MFMA16(af, bf, acc[cc]);
    }
  }
  #pragma unroll
  for (int cc = 0; cc < 4; ++cc) {
    int n = cbase + cc * 16 + lrow;                 // w
    float asc = (g == 1) ? L2E : 1.f;
    if (g == 3) asc = s_alpha[n] * L2E;
    #pragma unroll
    for (int rr = 0; rr < 4; ++rr) {
      int c = rt * 16 + lg * 4 + rr;
      lds_t[n][c] = f2bf(acc[cc][rr] * asc);
    }
  }
  __syncthreads();
  if (g == 0) {
    int c = tid >> 3, w0 = (tid & 7) * 16;
    int tw[8];
    #pragma unroll
    for (int i2 = 0; i2 < 8; ++i2)
      tw[i2] = (int)lds_t[w0 + 2 * i2][c] | ((int)lds_t[w0 + 2 * i2 + 1][c] << 16);
    int4* dst = reinterpret_cast<int4*>(qT + ((size_t)b * 32 + c) * 4096 + h * 128 + w0);
    dst[0] = make_int4(tw[0], tw[1], tw[2], tw[3]);
    dst[1] = make_int4(tw[4], tw[5], tw[6], tw[7]);
  } else if (tid < 128) {
    int w = tid;
    int tw[16];
    #pragma unroll
    for (int i2 = 0; i2 < 16; ++i2)
      tw[i2] = (int)lds_t[w][2 * i2] | ((int)lds_t[w][2 * i2 + 1] << 16);
    u16* base = (g == 2 || g == 4) ? Vc : KQ;
    int coff = (g >= 3) ? 32 : 0;
    int4* dst = reinterpret_cast<int4*>(base + ((size_t)b * 4096 + h * 128 + w) * 64 + coff);
    dst[0] = make_int4(tw[0],  tw[1],  tw[2],  tw[3]);
    dst[1] = make_int4(tw[4],  tw[5],  tw[6],  tw[7]);
    dst[2] = make_int4(tw[8],  tw[9],  tw[10], tw[11]);
    dst[3] = make_int4(tw[12], tw[13], tw[14], tw[15]);
  }
}

// ---------------- kernel 2: flash attention, j-split partials -------------
// Swapped QK^T: S^T-tile = mfma(A = V rows (j as M), B = KQ rows (i as N)).
// V rows are PERMUTED at staging: LDS row r holds global row j0 + pj(r),
//   pj(r) = (r&32) + ((r>>2)&3)*8 + ((r>>4)&1)*4 + (r&3)
// so lane (lrow,lg) holds P[i][j = w*32 + lg*8 + 0..7] across each sub-pair
// -> score fragments ARE the PV K=32 B-operand. Zero cross-lane ops in PV.
// Q slice for PV is staged per-iter into a swizzled LDS tile (4KB, dbuf):
// kills the 4x-wave-redundant 16-line global gathers that blew up L2 in R5.
// Each block covers j in [sp*512, sp*512+512); emits unnormalized partial
// (m, l, O) for its 64 i-rows.  pO layout: [b][sp][c][i] (i fastest).
__global__ __launch_bounds__(256, 6) void kattn(const u16* __restrict__ qT,
    const u16* __restrict__ KQ, const u16* __restrict__ Vc,
    u16* __restrict__ pO, float* __restrict__ pm, float* __restrict__ pl)
{
  __shared__ __align__(16) char lds_v[2][8192];
  __shared__ __align__(16) char lds_q[2][4096];
  const int b = blockIdx.y;
  const int i0 = blockIdx.x * 64;
  const int sp = blockIdx.z;
  const int jbase = sp * 512;
  const int tid = threadIdx.x, lane = tid & 63, wid = tid >> 6;
  const int lrow = lane & 15, lg = lane >> 4;

  const u16* KQb = KQ + (size_t)b * 4096 * 64;
  const u16* Vb  = Vc + (size_t)b * 4096 * 64;
  const u16* qTb = qT + (size_t)b * 32 * 4096;

  // KQ B-frags for this wave's 16 i-rows, direct from global (one-time)
  short8 bkq[2];
  {
    int r = i0 + wid * 16 + lrow;
    #pragma unroll
    for (int kc = 0; kc < 2; ++kc)
      bkq[kc] = *reinterpret_cast<const short8*>(KQb + (size_t)r * 64 + kc * 32 + lg * 8);
  }

  // staging geometry: thread owns V LDS rows sr, sr+32 (source permuted) and
  // Q LDS row sr; 16B chunk sx within the 128B row.
  const int sr = tid >> 3, sx = (tid & 7) * 16;
  const int pr = (((sr >> 2) & 3) << 3) + (((sr >> 4) & 1) << 2) + (sr & 3);

  // stage tile 0
  #pragma unroll
  for (int q = 0; q < 2; ++q) {
    int r = sr + q * 32, gr = pr + q * 32;
    int4 v = *reinterpret_cast<const int4*>(
        reinterpret_cast<const char*>(Vb + (size_t)(jbase + gr) * 64) + sx);
    *reinterpret_cast<int4*>(lds_v[0] + r * 128 + (sx ^ ((r & 7) << 4))) = v;
  }
  {
    int4 qv = *reinterpret_cast<const int4*>(
        qTb + (size_t)sr * 4096 + jbase + (tid & 7) * 8);
    *reinterpret_cast<int4*>(lds_q[0] + sr * 128 + (sx ^ ((sr & 7) << 4))) = qv;
  }
  __syncthreads();

  float m_run = -1e30f, l_run = 0.f;
  f32x4 accO[2] = {};
  int4 stgV[2], stgQ;

  for (int t = 0; t < 8; ++t) {
    const int buf = t & 1;
    if (t < 7) {                        // T14: issue next-tile loads early
      const u16* Vn = Vb + (size_t)(jbase + (t + 1) * 64) * 64;
      #pragma unroll
      for (int q = 0; q < 2; ++q) {
        int gr = pr + q * 32;
        stgV[q] = *reinterpret_cast<const int4*>(
            reinterpret_cast<const char*>(Vn + (size_t)gr * 64) + sx);
      }
      stgQ = *reinterpret_cast<const int4*>(
          qTb + (size_t)sr * 4096 + jbase + (t + 1) * 64 + (tid & 7) * 8);
    }
    // scores: 4 j-subtiles, K=64 in 2 chunks
    f32x4 st[4];
    __builtin_amdgcn_s_setprio(1);
    #pragma unroll
    for (int sub = 0; sub < 4; ++sub) {
      f32x4 a = {};
      #pragma unroll
      for (int kc = 0; kc < 2; ++kc) {
        int r = sub * 16 + lrow;
        int xs = kc * 64 + lg * 16;
        short8 av = *reinterpret_cast<const short8*>(
            lds_v[buf] + r * 128 + (xs ^ ((r & 7) << 4)));
        a = MFMA16(av, bkq[kc], a);
      }
      st[sub] = a;
    }
    __builtin_amdgcn_s_setprio(0);
    // PV A-frags from the swizzled Q tile (LDS latency overlaps softmax)
    short8 aq[2][2];
    #pragma unroll
    for (int w = 0; w < 2; ++w)
      #pragma unroll
      for (int ct = 0; ct < 2; ++ct) {
        int r = ct * 16 + lrow;
        int xs = w * 64 + lg * 16;
        aq[w][ct] = *reinterpret_cast<const short8*>(
            lds_q[buf] + r * 128 + (xs ^ ((r & 7) << 4)));
      }
    // online softmax (row i lane-local; reduce over lanes lrow,+16,+32,+48)
    float tm = -1e30f;
    #pragma unroll
    for (int sub = 0; sub < 4; ++sub)
      #pragma unroll
      for (int rr = 0; rr < 4; ++rr) tm = fmaxf(tm, st[sub][rr]);
    tm = fmaxf(tm, __shfl_xor(tm, 16, 64));
    tm = fmaxf(tm, __shfl_xor(tm, 32, 64));
    // defer-max (T13): skip rescale while tile max stays within 2^8 of m_run
    if (!__all((int)(tm <= m_run + 8.f))) {
      float m_new = fmaxf(m_run, tm);
      float scale = exp2f(m_run - m_new);
      l_run *= scale;
      #pragma unroll
      for (int ct = 0; ct < 2; ++ct)
        #pragma unroll
        for (int rr = 0; rr < 4; ++rr) accO[ct][rr] *= scale;
      m_run = m_new;
    }
    float ps = 0.f;
    #pragma unroll
    for (int sub = 0; sub < 4; ++sub)
      #pragma unroll
      for (int rr = 0; rr < 4; ++rr) {
        float p = exp2f(st[sub][rr] - m_run);
        st[sub][rr] = p;
        ps += p;
      }
    ps += __shfl_xor(ps, 16, 64);
    ps += __shfl_xor(ps, 32, 64);
    l_run += ps;

    // PV: O^T += mfma(A = Q-tile rows, B = P^T). B-frag is the packed scores
    // directly (V-row permutation made the lane->j map match the B layout).
    __builtin_amdgcn_s_setprio(1);
    #pragma unroll
    for (int w = 0; w < 2; ++w) {
      short8 bp = mk_frag(pack_bf2(st[2 * w][0],     st[2 * w][1]),
                          pack_bf2(st[2 * w][2],     st[2 * w][3]),
                          pack_bf2(st[2 * w + 1][0], st[2 * w + 1][1]),
                          pack_bf2(st[2 * w + 1][2], st[2 * w + 1][3]));
      #pragma unroll
      for (int ct = 0; ct < 2; ++ct)
        accO[ct] = MFMA16(aq[w][ct], bp, accO[ct]);
    }
    __builtin_amdgcn_s_setprio(0);

    if (t < 7) {
      #pragma unroll
      for (int q = 0; q < 2; ++q) {
        int r = sr + q * 32;
        *reinterpret_cast<int4*>(lds_v[buf ^ 1] + r * 128 + (sx ^ ((r & 7) << 4))) = stgV[q];
      }
      *reinterpret_cast<int4*>(lds_q[buf ^ 1] + sr * 128 + (sx ^ ((sr & 7) << 4))) = stgQ;
      __syncthreads();
    }
  }

  // write unnormalized partials; pO transposed [b][sp][c][i]
  const int i = i0 + wid * 16 + lrow;
  u16* pOb = pO + (size_t)((b * 8 + sp) * 32) * 4096;
  #pragma unroll
  for (int ct = 0; ct < 2; ++ct)
    #pragma unroll
    for (int rr = 0; rr < 4; ++rr)
      pOb[(size_t)(ct * 16 + lg * 4 + rr) * 4096 + i] = f2bf(accO[ct][rr]);
  if (lg == 0) {
    pm[(b * 8 + sp) * 4096 + i] = m_run;
    pl[(b * 8 + sp) * 4096 + i] = l_run;
  }
}

// ---------------- kernel 3: merge partials + final mix + residual ---------
// Block = 16 output rows (one b, one c, h in [h0,h0+16)).  Phase 1 reduces
// the 8 j-split partials for this c across the block's 2048 i-values into a
// 16x128 bf16 y-tile in LDS; phase 2 is the 128x128 GEMM + residual.
__global__ __launch_bounds__(128) void kout(const u16* __restrict__ pO,
    const float* __restrict__ pm, const float* __restrict__ pl,
    const u16* __restrict__ matT, const float* __restrict__ head,
    const float* __restrict__ tail, const int* __restrict__ flagp,
    float* __restrict__ out)
{
  __shared__ u16 ylds[16][136];          // padded rows (272 B) vs bank conflicts
  const int flag = *flagp;
  const float* X1 = flag ? head : tail;
  const u16* Bm = matT + 5 * 16384;
  const int tid = threadIdx.x;
  const int rbase = blockIdx.x * 16;
  const int b = rbase >> 10, c = (rbase >> 5) & 31, h0 = rbase & 31;
  const int ioff = h0 * 128 + tid * 16;  // this thread's 16 i-values

  // ---- phase 1: reduction over the 8 splits, 4 i at a time ----
  #pragma unroll
  for (int iq = 0; iq < 4; ++iq) {
    float4 msp[8];
    #pragma unroll
    for (int sp = 0; sp < 8; ++sp)
      msp[sp] = *reinterpret_cast<const float4*>(
          pm + (size_t)((b * 8 + sp) * 4096) + ioff + iq * 4);
    float4 M4 = msp[0];
    #pragma unroll
    for (int sp = 1; sp < 8; ++sp) {
      M4.x = fmaxf(M4.x, msp[sp].x); M4.y = fmaxf(M4.y, msp[sp].y);
      M4.z = fmaxf(M4.z, msp[sp].z); M4.w = fmaxf(M4.w, msp[sp].w);
    }
    float4 L4 = {0.f, 0.f, 0.f, 0.f}, y4 = {0.f, 0.f, 0.f, 0.f};
    #pragma unroll
    for (int sp = 0; sp < 8; ++sp) {
      float4 w4;
      w4.x = exp2f(msp[sp].x - M4.x); w4.y = exp2f(msp[sp].y - M4.y);
      w4.z = exp2f(msp[sp].z - M4.z); w4.w = exp2f(msp[sp].w - M4.w);
      float4 l4 = *reinterpret_cast<const float4*>(
          pl + (size_t)((b * 8 + sp) * 4096) + ioff + iq * 4);
      L4.x += w4.x * l4.x; L4.y += w4.y * l4.y;
      L4.z += w4.z * l4.z; L4.w += w4.w * l4.w;
      short4_t o4 = *reinterpret_cast<const short4_t*>(
          pO + (size_t)(((b * 8 + sp) * 32 + c)) * 4096 + ioff + iq * 4);
      y4.x += w4.x * bf2f(o4[0]); y4.y += w4.y * bf2f(o4[1]);
      y4.z += w4.z * bf2f(o4[2]); y4.w += w4.w * bf2f(o4[3]);
    }
    y4.x /= L4.x; y4.y /= L4.y; y4.z /= L4.z; y4.w /= L4.w;
    uint2 pk2;
    pk2.x = pack_bf2(y4.x, y4.y);
    pk2.y = pack_bf2(y4.z, y4.w);
    *reinterpret_cast<uint2*>(&ylds[tid >> 3][(tid & 7) * 16 + iq * 4]) = pk2;
  }
  __syncthreads();

  // ---- phase 2: out[rbase..rbase+16][:] = ylds @ W + X1 ----
  const int lane = tid & 63, wid = tid >> 6;
  const int lrow = lane & 15, lg = lane >> 4;
  const int ctbase = wid * 4;
  f32x4 acc[4] = {};
  #pragma unroll
  for (int k0 = 0; k0 < 128; k0 += 32) {
    short8 af = *reinterpret_cast<const short8*>(&ylds[lrow][k0 + lg * 8]);
    #pragma unroll
    for (int cc = 0; cc < 4; ++cc) {
      short8 bf = *reinterpret_cast<const short8*>(
          Bm + (size_t)((ctbase + cc) * 16 + lrow) * 128 + k0 + lg * 8);
      acc[cc] = MFMA16(af, bf, acc[cc]);
    }
  }
  #pragma unroll
  for (int cc = 0; cc < 4; ++cc)
    #pragma unroll
    for (int rr = 0; rr < 4; ++rr) {
      int row = rbase + lg * 4 + rr;
      int col = (ctbase + cc) * 16 + lrow;
      size_t idx = (size_t)row * 128 + col;
      out[idx] = acc[cc][rr] + X1[idx];
    }
}

// ---------------- launch ---------------------------------------------------
extern "C" void kernel_launch(void* const* d_in, const int* in_sizes, int n_in,
                              void* d_out, int out_size, void* d_ws, size_t ws_size,
                              hipStream_t stream)
{
  const float* head    = (const float*)d_in[0];
  const float* tail    = (const float*)d_in[1];
  const float* R_q     = (const float*)d_in[2];
  const float* R_k     = (const float*)d_in[3];
  const float* R_v     = (const float*)d_in[4];
  const float* R_W     = (const float*)d_in[5];
  const float* F_q     = (const float*)d_in[6];
  const float* F_k     = (const float*)d_in[7];
  const float* F_v     = (const float*)d_in[8];
  const float* F_W     = (const float*)d_in[9];
  const float* conv_w  = (const float*)d_in[10];
  const float* conv_b  = (const float*)d_in[11];
  const float* bn_w    = (const float*)d_in[12];
  const float* bn_b    = (const float*)d_in[13];
  const float* bn_mean = (const float*)d_in[14];
  const float* bn_var  = (const float*)d_in[15];
  const int*   flagp   = (const int*)d_in[16];
  float* out = (float*)d_out;

  char* ws = (char*)d_ws;
  u16*   matT = (u16*)(ws);               // 196608 B
  u16*   qT   = (u16*)(ws + 262144);      // 1 MB   (b,32,L) bf16
  u16*   KQ   = (u16*)(ws + 1310720);     // 2 MB   (b,L,64) bf16, pre-scaled log2e
  u16*   Vc   = (u16*)(ws + 3407872);     // 2 MB   (b,L,64) bf16
  u16*   pO   = (u16*)(ws + 6553600);     // 8 MB   [b][8][32][L] bf16 partial O
  float* pm   = (float*)(ws + 14942208);  // 512 KB [b][8][L] partial max
  float* pl   = (float*)(ws + 15466496);  // 512 KB [b][8][L] partial sum

  kprep <<<dim3(6, 8), 256, 0, stream>>>(R_q, R_k, R_v, R_W, F_q, F_k, F_v, F_W, flagp, matT);
  kproj <<<dim3(128, 5), 256, 0, stream>>>(head, tail, matT, conv_w, conv_b,
                                           bn_w, bn_b, bn_mean, bn_var,
                                           qT, KQ, Vc, flagp);
  kattn <<<dim3(64, 4, 8), 256, 0, stream>>>(qT, KQ, Vc, pO, pm, pl);
  kout  <<<256, 128, 0, stream>>>(pO, pm, pl, matT, head, tail, flagp, out);
}